// Round 1
// 1393.016 us; speedup vs baseline: 1.0822x; 1.0822x over previous
//
#include <hip/hip_runtime.h>

// Problem: B=8, S=4096, H=2048, M=256.
// Outputs (fp32, concat flat): combined [8,4096,4096], read_memory [8,4096,2048],
// new_memory [8,256,2048].

#define H_DIM 2048
#define M_SLOT 256
#define N_B 8
#define N_S 4096
#define N_ROWS 32768
#define TM 64
#define BK 32
#define N_CHUNK 64

typedef __bf16 bf16x8 __attribute__((ext_vector_type(8)));
typedef float floatx4 __attribute__((ext_vector_type(4)));

// ---- workspace layout (bytes); requires ws_size >= ~22.1 MB ----
#define WS_MEMQ_HI ((size_t)0)         // [256 q][256 n][8] bf16 hi : 1 MB
#define WS_MEMQ_LO ((size_t)1 << 20)   // same, lo                  : 1 MB
#define WS_MEMT2   ((size_t)2 << 20)   // [32 sq][2048 h][8] bf16   : 1 MB
#define WS_WQ      ((size_t)3 << 20)   // weights interleaved, 512 tiles * 32 KB = 16 MB
#define WS_XSUM    ((size_t)20 << 20)  // [8][2048] fp32 column sums of x
#define WS_WC      ((size_t)21 << 20)  // [8][2048] fp32 write_content

// ---- output offsets (floats) ----
#define OUT_COMBINED ((size_t)0)
#define OUT_READMEM  ((size_t)134217728)
#define OUT_NEWMEM   ((size_t)201326592)

// ---- LDS offsets, kernel gemm1_softmax ----
#define L_AHI 0        // [4 q][64 m][8] bf16 = 4 KB
#define L_ALO 4096
#define L_BHI 8192     // [4 q][256 n][8] bf16 = 16 KB
#define L_BLO 24576
#define L_COLSUM 40960 // [2048] fp32 = 8 KB
#define L_SMAX 49152   // [4 wave][64 row] fp32
#define L_SSUM 50176
#define L_GMAX 51200   // [64] fp32
#define L_GINV 51456   // [64] fp32
#define L_TOTAL 51712

// ---- LDS offsets, kernel gemm2 (A 32K + double-buffered B 2x16K) ----
#define G2_A 0
#define G2_B0 32768
#define G2_B1 49152
#define G2_TOTAL 65536

__device__ __forceinline__ floatx4 mfma16(bf16x8 a, bf16x8 b, floatx4 c) {
  return __builtin_amdgcn_mfma_f32_16x16x32_bf16(a, b, c, 0, 0, 0);
}

// Async global->LDS, 16B per lane. LDS dest is lane-linear (base + lane*16),
// matching the HW wave-uniform-base + lane*size write pattern.
__device__ __forceinline__ void async16(const void* g, void* l) {
  __builtin_amdgcn_global_load_lds(
      (const __attribute__((address_space(1))) void*)g,
      (__attribute__((address_space(3))) void*)l, 16, 0, 0);
}

// --------------------------------------------------------------------------
// Prep: split/round memory into MFMA-B-fragment-friendly interleaved layouts.
// memQ[q][n][j]  = split(mem[n][q*8+j])   (hi+lo)   -> B operand of GEMM1
// memT2[sq][h][j]= bf16(mem[sq*8+j][h])             -> B operand of GEMM2
// --------------------------------------------------------------------------
__global__ __launch_bounds__(256) void prep_kernel(const float* __restrict__ mem,
                                                   unsigned char* __restrict__ ws) {
  const int t = threadIdx.x;
  const int blk = blockIdx.x;
  if (blk < 256) {
    const int idx = blk * 256 + t;  // 0..65535
    const int q = idx >> 8, n = idx & 255;
    const float* src = mem + (size_t)n * H_DIM + q * 8;
    bf16x8 hv, lv;
#pragma unroll
    for (int j = 0; j < 8; j++) {
      float v = src[j];
      __bf16 hh = (__bf16)v;
      hv[j] = hh;
      lv[j] = (__bf16)(v - (float)hh);
    }
    *(bf16x8*)(ws + WS_MEMQ_HI + (size_t)idx * 16) = hv;
    *(bf16x8*)(ws + WS_MEMQ_LO + (size_t)idx * 16) = lv;
  } else {
    const int idx = (blk - 256) * 256 + t;  // 0..65535
    const int sq = idx >> 11, h = idx & 2047;
    bf16x8 v;
#pragma unroll
    for (int j = 0; j < 8; j++)
      v[j] = (__bf16)mem[(size_t)(sq * 8 + j) * H_DIM + h];
    *(bf16x8*)(ws + WS_MEMT2 + (size_t)idx * 16) = v;
  }
}

// --------------------------------------------------------------------------
// GEMM1 (bf16x3 split -> fp32-accurate scores) + softmax + weight export.
// Also: copies x into combined[:, :H] and accumulates column sums of x.
// Pipeline per chunk:
//   sync1 -> issue async B stage (global_load_lds, no reg round-trip)
//         -> consume prefetched x regs (combined copy, colsum, hi/lo split)
//   sync2 -> issue x prefetch for c+1 (hides under MFMA)
//         -> ds_read frags + 48 MFMA
// --------------------------------------------------------------------------
__global__ __launch_bounds__(256, 2) void gemm1_softmax(
    const float* __restrict__ x, unsigned char* __restrict__ ws,
    float* __restrict__ out) {
  __shared__ __align__(16) unsigned char smem[L_TOTAL];
  const int t = threadIdx.x;
  const int orig = blockIdx.x;                 // 0..511
  const int blk = (orig & 7) * 64 + (orig >> 3);  // XCD-contiguous (512%8==0)
  const int row0 = blk * TM;
  const int bidx = blk >> 6;         // batch index (64 tiles per batch)
  const int wv = t >> 6, lane = t & 63, r = lane & 15, qd = lane >> 4;

  float* colsum = (float*)(smem + L_COLSUM);
  for (int i = t; i < H_DIM; i += 256) colsum[i] = 0.0f;

  floatx4 acc[4][4];
#pragma unroll
  for (int a = 0; a < 4; a++)
#pragma unroll
    for (int b = 0; b < 4; b++) {
      floatx4 z = {0.f, 0.f, 0.f, 0.f};
      acc[a][b] = z;
    }

  const int xr = t >> 2, kq = t & 3;
  const float* xbase = x + (size_t)(row0 + xr) * H_DIM + kq * 8;
  float* cbase = out + OUT_COMBINED + (size_t)(row0 + xr) * 4096 + kq * 8;

  // prefetch x tile for chunk 0
  float4 v0 = *(const float4*)(xbase);
  float4 v1 = *(const float4*)(xbase + 4);

  for (int c = 0; c < N_CHUNK; c++) {
    __syncthreads();  // prev chunk's LDS consumers done (also drains x prefetch)
    // ---- stage memory tile: async L2 -> LDS, linear layout, no VGPR round-trip
    {
      const unsigned char* gh = ws + WS_MEMQ_HI + (size_t)c * 16384;
      const unsigned char* gl = ws + WS_MEMQ_LO + (size_t)c * 16384;
#pragma unroll
      for (int i = 0; i < 4; i++) {
        const int p = i * 256 + t;
        async16(gh + (size_t)p * 16, smem + L_BHI + p * 16);
        async16(gl + (size_t)p * 16, smem + L_BLO + p * 16);
      }
    }
    // ---- consume prefetched x: copy to combined + colsum + hi/lo bf16 LDS ----
    *(float4*)(cbase + c * BK) = v0;
    *(float4*)(cbase + c * BK + 4) = v1;
    float vv[8] = {v0.x, v0.y, v0.z, v0.w, v1.x, v1.y, v1.z, v1.w};
#pragma unroll
    for (int j = 0; j < 8; j++) atomicAdd(&colsum[c * BK + kq * 8 + j], vv[j]);
    bf16x8 hv, lv;
#pragma unroll
    for (int j = 0; j < 8; j++) {
      __bf16 hh = (__bf16)vv[j];
      hv[j] = hh;
      lv[j] = (__bf16)(vv[j] - (float)hh);
    }
    *(bf16x8*)(smem + L_AHI + kq * 1024 + xr * 16) = hv;
    *(bf16x8*)(smem + L_ALO + kq * 1024 + xr * 16) = lv;
    __syncthreads();  // drains async B stage + A ds_writes
    // ---- prefetch next x tile; HBM latency hides under the MFMA phase ----
    if (c + 1 < N_CHUNK) {
      v0 = *(const float4*)(xbase + (size_t)(c + 1) * BK);
      v1 = *(const float4*)(xbase + (size_t)(c + 1) * BK + 4);
    }
    // ---- fragments & MFMA (3 split products into one accumulator) ----
    bf16x8 ah[4], al[4], bh[4], bl[4];
#pragma unroll
    for (int rt = 0; rt < 4; rt++) {
      ah[rt] = *(const bf16x8*)(smem + L_AHI + qd * 1024 + (rt * 16 + r) * 16);
      al[rt] = *(const bf16x8*)(smem + L_ALO + qd * 1024 + (rt * 16 + r) * 16);
    }
#pragma unroll
    for (int ct = 0; ct < 4; ct++) {
      int n = wv * 64 + ct * 16 + r;
      bh[ct] = *(const bf16x8*)(smem + L_BHI + qd * 4096 + n * 16);
      bl[ct] = *(const bf16x8*)(smem + L_BLO + qd * 4096 + n * 16);
    }
#pragma unroll
    for (int rt = 0; rt < 4; rt++)
#pragma unroll
      for (int ct = 0; ct < 4; ct++) {
        acc[rt][ct] = mfma16(ah[rt], bh[ct], acc[rt][ct]);
        acc[rt][ct] = mfma16(ah[rt], bl[ct], acc[rt][ct]);
        acc[rt][ct] = mfma16(al[rt], bh[ct], acc[rt][ct]);
      }
  }
  // ---- flush column sums (last colsum writes were before the last barrier) ----
  {
    float* xsum = (float*)(ws + WS_XSUM);
    for (int i = t; i < H_DIM; i += 256)
      atomicAdd(&xsum[bidx * H_DIM + i], colsum[i]);
  }
  // ---- softmax over all 256 slots per row ----
  // C/D layout: col = lane&15, row = (lane>>4)*4 + reg  [m89-verified]
  float* smax = (float*)(smem + L_SMAX);
  float* ssum = (float*)(smem + L_SSUM);
  float* gmax = (float*)(smem + L_GMAX);
  float* ginv = (float*)(smem + L_GINV);
#pragma unroll
  for (int rt = 0; rt < 4; rt++)
#pragma unroll
    for (int rg = 0; rg < 4; rg++) {
      float m = fmaxf(fmaxf(acc[rt][0][rg], acc[rt][1][rg]),
                      fmaxf(acc[rt][2][rg], acc[rt][3][rg]));
#pragma unroll
      for (int off = 1; off < 16; off <<= 1) m = fmaxf(m, __shfl_xor(m, off));
      if (r == 0) smax[wv * 64 + rt * 16 + qd * 4 + rg] = m;
    }
  __syncthreads();
  if (t < 64)
    gmax[t] = fmaxf(fmaxf(smax[t], smax[64 + t]),
                    fmaxf(smax[128 + t], smax[192 + t]));
  __syncthreads();
#pragma unroll
  for (int rt = 0; rt < 4; rt++)
#pragma unroll
    for (int rg = 0; rg < 4; rg++) {
      const int row = rt * 16 + qd * 4 + rg;
      const float gm = gmax[row];
      float s = 0.f;
#pragma unroll
      for (int ct = 0; ct < 4; ct++) {
        float e = __expf(acc[rt][ct][rg] - gm);
        acc[rt][ct][rg] = e;
        s += e;
      }
#pragma unroll
      for (int off = 1; off < 16; off <<= 1) s += __shfl_xor(s, off);
      if (r == 0) ssum[wv * 64 + row] = s;
    }
  __syncthreads();
  if (t < 64)
    ginv[t] = 1.0f / (ssum[t] + ssum[64 + t] + ssum[128 + t] + ssum[192 + t]);
  __syncthreads();
  // ---- weights -> LDS (row-major, stride 264 bf16 = 528 B, 16B-aligned rows) ----
  // (aliases the now-dead fragment staging region)
  __bf16* wl = (__bf16*)smem;
#pragma unroll
  for (int rt = 0; rt < 4; rt++)
#pragma unroll
    for (int rg = 0; rg < 4; rg++) {
      const int row = rt * 16 + qd * 4 + rg;
      const float gi = ginv[row];
#pragma unroll
      for (int ct = 0; ct < 4; ct++) {
        const int col = wv * 64 + ct * 16 + r;
        wl[row * 264 + col] = (__bf16)(acc[rt][ct][rg] * gi);
      }
    }
  __syncthreads();
  // ---- export weights, interleaved [q=slot/8][row][8] for GEMM2 A-frags ----
  unsigned char* wq = ws + WS_WQ + (size_t)blk * 32768;
#pragma unroll
  for (int i = 0; i < 8; i++) {
    const int p = i * 256 + t;          // p = q*64 + rowl
    const int q = p >> 6, rowl = p & 63;
    *(uint4*)(wq + (size_t)p * 16) =
        *(const uint4*)(smem + ((size_t)rowl * 264 + q * 8) * 2);
  }
}

// --------------------------------------------------------------------------
// GEMM2: read = weights[64 rows x 256 slots] @ mem[256 x H], h-chunk of 256.
// Async-staged A + double-buffered async B, ONE barrier per K-step:
// issue next-B -> compute current -> barrier (drains prefetch).
// Grid: 512 row-tiles x 8 h-chunks, XCD-swizzled so hc-siblings share L2.
// --------------------------------------------------------------------------
__global__ __launch_bounds__(256, 2) void gemm2_kernel(
    const unsigned char* __restrict__ ws, float* __restrict__ out) {
  __shared__ __align__(16) unsigned char smem[G2_TOTAL];
  const int t = threadIdx.x;
  const int orig = blockIdx.x;                     // 0..4095
  const int lb = (orig & 7) * 512 + (orig >> 3);   // XCD-contiguous (4096%8==0)
  const int rtb = lb >> 3, hc = lb & 7;
  const int row0 = rtb * 64, h0 = hc * 256;
  const int wv = t >> 6, lane = t & 63, r = lane & 15, qd = lane >> 4;

  // stage A2 (weights, already interleaved): 32 KB, async
  const unsigned char* wq = ws + WS_WQ + (size_t)rtb * 32768;
#pragma unroll
  for (int i = 0; i < 8; i++) {
    const int p = i * 256 + t;
    async16(wq + (size_t)p * 16, smem + G2_A + p * 16);
  }
  // stage B2 slice ks=0 into buf0, async
#pragma unroll
  for (int i = 0; i < 4; i++) {
    const int p = i * 256 + t;
    const int sql = p >> 8, hh = p & 255;
    async16(ws + WS_MEMT2 + ((size_t)sql * 2048 + h0 + hh) * 16,
            smem + G2_B0 + p * 16);
  }
  floatx4 acc[4][4];
#pragma unroll
  for (int a = 0; a < 4; a++)
#pragma unroll
    for (int b = 0; b < 4; b++) {
      floatx4 z = {0.f, 0.f, 0.f, 0.f};
      acc[a][b] = z;
    }
  __syncthreads();  // drains A + B0

  for (int ks = 0; ks < 8; ks++) {
    const int boff = (ks & 1) ? G2_B1 : G2_B0;
    const int noff = (ks & 1) ? G2_B0 : G2_B1;
    if (ks + 1 < 8) {
      // prefetch next B slice into the other buffer (reads of it finished
      // before the previous barrier)
#pragma unroll
      for (int i = 0; i < 4; i++) {
        const int p = i * 256 + t;
        const int sql = p >> 8, hh = p & 255;
        async16(ws + WS_MEMT2 +
                    ((size_t)((ks + 1) * 4 + sql) * 2048 + h0 + hh) * 16,
                smem + noff + p * 16);
      }
    }
    bf16x8 a[4], b[4];
#pragma unroll
    for (int rt = 0; rt < 4; rt++)
      a[rt] = *(const bf16x8*)(smem + G2_A + (ks * 4 + qd) * 1024 +
                               (rt * 16 + r) * 16);
#pragma unroll
    for (int ct = 0; ct < 4; ct++)
      b[ct] = *(const bf16x8*)(smem + boff + qd * 4096 +
                               (wv * 64 + ct * 16 + r) * 16);
#pragma unroll
    for (int rt = 0; rt < 4; rt++)
#pragma unroll
      for (int ct = 0; ct < 4; ct++)
        acc[rt][ct] = mfma16(a[rt], b[ct], acc[rt][ct]);
    __syncthreads();  // drains next-B prefetch; orders buffer reuse
  }
  // epilogue: two destinations
#pragma unroll
  for (int rt = 0; rt < 4; rt++)
#pragma unroll
    for (int ct = 0; ct < 4; ct++)
#pragma unroll
      for (int rg = 0; rg < 4; rg++) {
        const int R = row0 + rt * 16 + qd * 4 + rg;
        const int hcol = h0 + wv * 64 + ct * 16 + r;
        const float v = acc[rt][ct][rg];
        out[OUT_READMEM + (size_t)R * 2048 + hcol] = v;
        out[OUT_COMBINED + (size_t)R * 4096 + 2048 + hcol] = v;
      }
}

// --------------------------------------------------------------------------
// write_content[b][j] = b_write[j] + (1/S) * sum_h xsum[b][h] * w_write[j][h]
// Grid: 256 blocks x 256 threads (all CUs). 32 threads per j:
// 8 batches x 4-way K-split, shfl-reduced.
// --------------------------------------------------------------------------
__global__ __launch_bounds__(256) void write_gemm(
    const float* __restrict__ w_write, const float* __restrict__ b_write,
    unsigned char* __restrict__ ws) {
  const int t = threadIdx.x;
  const int j = blockIdx.x * 8 + (t >> 5);  // 0..2047
  const int pr = t & 31;
  const int b = pr & 7;
  const int kq = pr >> 3;                   // 4-way K split
  const float* xsum = (const float*)(ws + WS_XSUM);
  const float* wr = w_write + (size_t)j * H_DIM + kq * 512;
  const float* xp = xsum + (size_t)b * H_DIM + kq * 512;
  float a0 = 0.f;
  for (int h = 0; h < 512; h += 4) {
    float4 w4 = *(const float4*)(wr + h);
    float4 x0 = *(const float4*)(xp + h);
    a0 += w4.x * x0.x + w4.y * x0.y + w4.z * x0.z + w4.w * x0.w;
  }
  // reduce over kq (t bits 3,4 — intra-wave)
  a0 += __shfl_xor(a0, 8);
  a0 += __shfl_xor(a0, 16);
  if (kq == 0) {
    float* wc = (float*)(ws + WS_WC);
    wc[(size_t)b * H_DIM + j] = a0 * (1.0f / 4096.f) + b_write[j];
  }
}

// --------------------------------------------------------------------------
// new_memory[b][m][h] = 0.9*mem[m][h] + 0.1*write_content[b][h]
// --------------------------------------------------------------------------
__global__ __launch_bounds__(256) void newmem_kernel(
    const float* __restrict__ mem, const unsigned char* __restrict__ ws,
    float* __restrict__ out) {
  const int i4 = blockIdx.x * 256 + threadIdx.x;  // < 1048576
  const size_t e = (size_t)i4 * 4;
  const int b = (int)(e >> 19);
  const int rem = (int)(e & 524287);
  const int h = (int)(e & 2047);
  const float4 mv = *(const float4*)(mem + rem);
  const float* wc = (const float*)(ws + WS_WC);
  const float4 wv = *(const float4*)(wc + b * H_DIM + h);
  float4 o;
  o.x = 0.9f * mv.x + 0.1f * wv.x;
  o.y = 0.9f * mv.y + 0.1f * wv.y;
  o.z = 0.9f * mv.z + 0.1f * wv.z;
  o.w = 0.9f * mv.w + 0.1f * wv.w;
  *(float4*)(out + OUT_NEWMEM + e) = o;
}

extern "C" void kernel_launch(void* const* d_in, const int* in_sizes, int n_in,
                              void* d_out, int out_size, void* d_ws, size_t ws_size,
                              hipStream_t stream) {
  const float* x = (const float*)d_in[0];
  const float* memory = (const float*)d_in[1];
  const float* w_write = (const float*)d_in[2];
  const float* b_write = (const float*)d_in[3];
  float* out = (float*)d_out;
  unsigned char* ws = (unsigned char*)d_ws;

  // 1) layout/precision prep of `memory`
  prep_kernel<<<512, 256, 0, stream>>>(memory, ws);
  // 2) zero the x column-sum accumulator (ws is poisoned 0xAA before each call)
  hipMemsetAsync(ws + WS_XSUM, 0, (size_t)N_B * H_DIM * sizeof(float), stream);
  // 3) scores (bf16x3) + softmax + weight export + x-copy + column sums
  gemm1_softmax<<<512, 256, 0, stream>>>(x, ws, out);
  // 4) read_memory = weights @ memory (+ combined second half)
  gemm2_kernel<<<4096, 256, 0, stream>>>(ws, out);
  // 5) write_content GEMV (all CUs, K-split)
  write_gemm<<<256, 256, 0, stream>>>(w_write, b_write, ws);
  // 6) new_memory EMA
  newmem_kernel<<<4096, 256, 0, stream>>>(memory, ws, out);
}